// Round 16
// baseline (391.006 us; speedup 1.0000x reference)
//
#include <hip/hip_runtime.h>

typedef _Float16 f16x8 __attribute__((ext_vector_type(8)));
typedef _Float16 f16x4 __attribute__((ext_vector_type(4)));
typedef __fp16   fp16x2 __attribute__((ext_vector_type(2)));
typedef float    f32x4 __attribute__((ext_vector_type(4)));
typedef unsigned int u32x2 __attribute__((ext_vector_type(2)));

__device__ __forceinline__ f32x4 mfma32(f16x8 a, f16x8 b, f32x4 c) {
  return __builtin_amdgcn_mfma_f32_16x16x32_f16(a, b, c, 0, 0, 0);
}
__device__ __forceinline__ f32x4 mfma16(f16x4 a, f16x4 b, f32x4 c) {
#if __has_builtin(__builtin_amdgcn_mfma_f32_16x16x16f16)
  return __builtin_amdgcn_mfma_f32_16x16x16f16(a, b, c, 0, 0, 0);
#else
  f32x4 d;
  asm volatile("v_mfma_f32_16x16x16_f16 %0, %1, %2, %3"
               : "=v"(d) : "v"(a), "v"(b), "v"(c));
  return d;
#endif
}

__device__ __forceinline__ unsigned pk2(float a, float b) {
  union { fp16x2 h; unsigned u; } cv;
  cv.h = __builtin_amdgcn_cvt_pkrtz(a, b);
  return cv.u;
}

// hardware transpose read: per-lane vaddr (32-bit LDS byte offset) = base + 8*lane;
// delivers, for lane l, elems j=0..3 = lds_elem[(l&15) + 16*j + 64*(l>>4)] rel. to base
#define TR_READ(dst, addr, OFF) \
  asm volatile("ds_read_b64_tr_b16 %0, %1 offset:" OFF \
               : "=v"(dst) : "v"(addr) : "memory")

// ---- pre-convert weights to fp16 in workspace (L2-resident reuse) ----
__global__ void cvt_weights(const float* __restrict__ qw, const float* __restrict__ cw,
                            _Float16* __restrict__ wq, _Float16* __restrict__ wc) {
  const int i = blockIdx.x * 256 + threadIdx.x;
  if (i < 384 * 128) wq[i] = (_Float16)qw[i];
  if (i < 128 * 128) wc[i] = (_Float16)cw[i];
}

// One 4x4x4 window per block; 512 threads = 8 waves; wave wv owns head h=wv.
// R12-R15 plateau at {occ 42%, VALU 24%, MFMA 9%}: intra-wave ILP exhausted,
// occupancy LDS-capped at 2 blocks/CU (64KB). R16: delete the per-wave v LDS
// region — v is packed to 8 temps in the v-GEMM phase and immediately
// g-group-shuffled into av0/av1 MFMA fragments (R11's verified lane mapping);
// temps die, steady regs = R12. wsm 6KB->4KB => LDS 48KB => 3 blocks/CU
// (24 waves, +50% latency hiding). __launch_bounds__(512,6) = 24 waves/CU
// (85-reg budget — spill watchdog: WRITE_SIZE > 170MB reverts this).
// LDS (48KB, 3 blocks/CU):
//   xsm [16KB]: x-window / o buffer [64 t][128 ch], byte = t*256 + (2ch ^ ((t&15)<<4))
//   wsm[wv] (4KB/wave): [0,2048) k as [si][16ch][16tok] (tr-read layout),
//                       [2048,4096) q same; P chunk [32t][64s] overwrites [0,4096):
//                         byte = t_local*128 + (2s ^ ((l15&7)<<4))
__global__ void __launch_bounds__(512, 6)
win_attn(const float* __restrict__ xg, const _Float16* __restrict__ wq,
         const float* __restrict__ qbias, const _Float16* __restrict__ wc,
         const float* __restrict__ cb, float* __restrict__ outg)
{
  __shared__ char xsm[16384];
  __shared__ char wsm[8][4096];

  const int tid  = threadIdx.x;
  const int lane = tid & 63;
  const int wv   = tid >> 6;          // 0..7 = head
  const int l15  = lane & 15;
  const int g    = lane >> 4;

  // XCD-bijective swizzle (4096 % 8 == 0): contiguous ww-ranges per XCD
  const int raw = blockIdx.x;
  const int wid = ((raw & 7) << 9) | (raw >> 3);
  const int ww = wid & 15, hh = (wid >> 4) & 15, dd = (wid >> 8) & 7, bb = wid >> 11;

  const f32x4 fz = {0.f, 0.f, 0.f, 0.f};

  // ---------------- stage x window -> xsm (fp16, swizzled token-major) ----------------
  {
    const int m4 = lane & 3, q4 = lane >> 2;
    const int i0 = q4 >> 2, i1 = q4 & 3;
    const int z = dd * 4 + i0, y = hh * 4 + i1;
    const bool yv   = (y < 62);
    const bool full = (ww < 15);
    float va[4][4];
#pragma unroll
    for (int it = 0; it < 4; ++it) {           // issue all global loads first
      const int c = wv * 16 + it * 4 + m4;
      const float* src = xg + (((size_t)(bb * 128 + c) * 32 + (size_t)z) * 3844
                               + (size_t)(y * 62 + ww * 4));
      float a0 = 0.f, a1 = 0.f, a2 = 0.f, a3 = 0.f;
      if (yv) {
        const float2 lo = *reinterpret_cast<const float2*>(src);
        a0 = lo.x; a1 = lo.y;
        if (full) {
          const float2 hi = *reinterpret_cast<const float2*>(src + 2);
          a2 = hi.x; a3 = hi.y;
        }
      }
      va[it][0] = a0; va[it][1] = a1; va[it][2] = a2; va[it][3] = a3;
    }
#pragma unroll
    for (int it = 0; it < 4; ++it) {           // 4x4 lane-quad transpose, packed b64 write
      float v0 = va[it][0], v1 = va[it][1], v2 = va[it][2], v3 = va[it][3];
      float t0 = __shfl_xor((m4 & 1) ? v0 : v1, 1);
      float t1 = __shfl_xor((m4 & 1) ? v2 : v3, 1);
      if (m4 & 1) { v0 = t0; v2 = t1; } else { v1 = t0; v3 = t1; }
      float t2 = __shfl_xor((m4 & 2) ? v0 : v2, 2);
      float t3 = __shfl_xor((m4 & 2) ? v1 : v3, 2);
      if (m4 & 2) { v0 = t2; v1 = t3; } else { v2 = t2; v3 = t3; }
      f16x4 pk; pk[0] = (_Float16)v0; pk[1] = (_Float16)v1;
                pk[2] = (_Float16)v2; pk[3] = (_Float16)v3;
      const int c0 = wv * 16 + it * 4;         // lane holds xs[t=lane][c0..c0+3]
      *reinterpret_cast<f16x4*>(xsm + ((lane * 256 + 2 * c0) ^ ((lane & 15) << 4))) = pk;
    }
  }
  __syncthreads();

  // ---------------- this wave's head: QKV GEMM -> attention ----------------
  char* sb = wsm[wv];
  const unsigned sb32 = (unsigned)(unsigned long long)sb;   // LDS byte offset
  const unsigned trb  = sb32 + 8u * (unsigned)lane;
  const int vswz = (l15 & 7) << 4;              // P-chunk swizzle

  unsigned long long pm = 0ull;                     // pad flag per token
  if (hh == 15) pm |= 0xFF00FF00FF00FF00ull;        // i1 >= 2
  if (ww == 15) pm |= 0xCCCCCCCCCCCCCCCCull;        // i2 >= 2

  const float LOG2E = 1.4426950408889634f;
  const int swzA = l15 << 4;

  f16x8 av0, av1;   // v fragments for PV (A-operand), built in the co==2 phase

  // ---- QKV GEMM, one 16-col block at a time: co 0=q, 1=k, 2=v ----
#pragma unroll
  for (int co = 0; co < 3; ++co) {
    f32x4 acc[4] = {fz, fz, fz, fz};
    const int col = co * 128 + wv * 16 + l15;
#pragma unroll
    for (int kk = 0; kk < 4; ++kk) {
      const f16x8 bfr = *reinterpret_cast<const f16x8*>(wq + col * 128 + kk * 32 + g * 8);
#pragma unroll
      for (int ri = 0; ri < 4; ++ri) {
        const f16x8 a = *reinterpret_cast<const f16x8*>(
            xsm + (ri * 16 + l15) * 256 + ((kk * 64 + g * 16) ^ swzA));
        acc[ri] = mfma32(a, bfr, acc[ri]);
      }
    }
    const float bias = qbias[col];

    if (co == 2) {
      // pack v: vp[ri][p] = f16x2 of v[t = ri*16+g*4+{2p,2p+1}][c = l15],
      // then redistribute in-register to av fragments (R11 mapping):
      // av{kc}: lane (g,l15) gets v[s = kc*32 + g*8 + j][c = l15], j=0..7
      unsigned vp[4][2];
#pragma unroll
      for (int ri = 0; ri < 4; ++ri) {
        vp[ri][0] = pk2(acc[ri][0] + bias, acc[ri][1] + bias);
        vp[ri][1] = pk2(acc[ri][2] + bias, acc[ri][3] + bias);
      }
      const int srcA = l15 + 32 * (g & 1);
      const bool hi = (g >= 2);
      {
        const unsigned a0 = __shfl(vp[0][0], srcA);
        const unsigned a1 = __shfl(vp[0][1], srcA);
        const unsigned a2 = __shfl(vp[0][0], srcA + 16);
        const unsigned a3 = __shfl(vp[0][1], srcA + 16);
        const unsigned b0 = __shfl(vp[1][0], srcA);
        const unsigned b1 = __shfl(vp[1][1], srcA);
        const unsigned b2 = __shfl(vp[1][0], srcA + 16);
        const unsigned b3 = __shfl(vp[1][1], srcA + 16);
        union { unsigned w[4]; f16x8 v; } u;
        u.w[0] = hi ? b0 : a0; u.w[1] = hi ? b1 : a1;
        u.w[2] = hi ? b2 : a2; u.w[3] = hi ? b3 : a3;
        av0 = u.v;
      }
      {
        const unsigned a0 = __shfl(vp[2][0], srcA);
        const unsigned a1 = __shfl(vp[2][1], srcA);
        const unsigned a2 = __shfl(vp[2][0], srcA + 16);
        const unsigned a3 = __shfl(vp[2][1], srcA + 16);
        const unsigned b0 = __shfl(vp[3][0], srcA);
        const unsigned b1 = __shfl(vp[3][1], srcA);
        const unsigned b2 = __shfl(vp[3][0], srcA + 16);
        const unsigned b3 = __shfl(vp[3][1], srcA + 16);
        union { unsigned w[4]; f16x8 v; } u;
        u.w[0] = hi ? b0 : a0; u.w[1] = hi ? b1 : a1;
        u.w[2] = hi ? b2 : a2; u.w[3] = hi ? b3 : a3;
        av1 = u.v;
      }
    } else {
      // q/k -> tr-read layout: element off = si*256 + ch*16 + (tok&15)
      const int base = (co == 0) ? 2048 : 0;
      const float sc = (co == 0) ? 0.25f : 1.0f;   // fold softmax scale into q
#pragma unroll
      for (int ri = 0; ri < 4; ++ri) {
        const int off = ri * 512 + l15 * 32 + g * 8;  // bytes
        u32x2 w;
        w[0] = pk2((acc[ri][0] + bias) * sc, (acc[ri][1] + bias) * sc);
        w[1] = pk2((acc[ri][2] + bias) * sc, (acc[ri][3] + bias) * sc);
        *reinterpret_cast<u32x2*>(sb + base + off) = w;
      }
    }
  }
  asm volatile("s_waitcnt lgkmcnt(0)" ::: "memory");

  // ---- tr reads: ka[si] = k[s=si*16+l15][ch=g*4+j], qa[tj] = q[t=tj*16+l15][ch=g*4+j]
  f16x4 ka[4], qa[4];
  TR_READ(ka[0], trb, "0");
  TR_READ(ka[1], trb, "512");
  TR_READ(ka[2], trb, "1024");
  TR_READ(ka[3], trb, "1536");
  TR_READ(qa[0], trb, "2048");
  TR_READ(qa[1], trb, "2560");
  TR_READ(qa[2], trb, "3072");
  TR_READ(qa[3], trb, "3584");
  asm volatile("s_waitcnt lgkmcnt(0)" ::: "memory");
  __builtin_amdgcn_sched_barrier(0);           // rule #18: fence tr_read -> mfma

  unsigned opk[4][2];                       // packed o (this head), all static idx
  // ---- two tj-pair chunks: S^T -> softmax -> P chunk -> PV ----
#pragma unroll
  for (int tjp = 0; tjp < 2; ++tjp) {
    const int tj0 = 2 * tjp, tj1 = 2 * tjp + 1;
    // st2[si][tjc]: s = si*16+g*4+r, t = (tjp*2+tjc)*16 + l15
    f32x4 st2[4][2];
#pragma unroll
    for (int si = 0; si < 4; ++si) {
      st2[si][0] = mfma16(ka[si], qa[tj0], fz);
      st2[si][1] = mfma16(ka[si], qa[tj1], fz);
    }

    // pad mask: -1000 where pad(s) != pad(t)
    if (pm) {
#pragma unroll
      for (int tjc = 0; tjc < 2; ++tjc) {
        const int t = (2 * tjp + tjc) * 16 + l15;
        const unsigned ft = (unsigned)(pm >> t) & 1u;
#pragma unroll
        for (int si = 0; si < 4; ++si)
#pragma unroll
          for (int r = 0; r < 4; ++r) {
            const int s = si * 16 + g * 4 + r;
            const unsigned fs = (unsigned)(pm >> s) & 1u;
            if (fs != ft) st2[si][tjc][r] -= 1000.f;
          }
      }
    }

    // softmax over s (16 lane-local + 2 shfl), per tjc
#pragma unroll
    for (int tjc = 0; tjc < 2; ++tjc) {
      float mx = st2[0][tjc][0];
#pragma unroll
      for (int si = 0; si < 4; ++si)
#pragma unroll
        for (int r = 0; r < 4; ++r) mx = fmaxf(mx, st2[si][tjc][r]);
      mx = fmaxf(mx, __shfl_xor(mx, 16));
      mx = fmaxf(mx, __shfl_xor(mx, 32));
      float sum = 0.f;
#pragma unroll
      for (int si = 0; si < 4; ++si)
#pragma unroll
        for (int r = 0; r < 4; ++r) {
          const float e = __builtin_amdgcn_exp2f((st2[si][tjc][r] - mx) * LOG2E);
          st2[si][tjc][r] = e; sum += e;
        }
      sum += __shfl_xor(sum, 16);
      sum += __shfl_xor(sum, 32);
      const float inv = __builtin_amdgcn_rcpf(sum);
#pragma unroll
      for (int si = 0; si < 4; ++si)
#pragma unroll
        for (int r = 0; r < 4; ++r) st2[si][tjc][r] *= inv;
    }

    // write P chunk [32 t_local][64 s]: byte = t_local*128 + (2s ^ vswz)
#pragma unroll
    for (int tjc = 0; tjc < 2; ++tjc) {
      const int tl = tjc * 16 + l15;
#pragma unroll
      for (int si = 0; si < 4; ++si) {
        u32x2 w;
        w[0] = pk2(st2[si][tjc][0], st2[si][tjc][1]);
        w[1] = pk2(st2[si][tjc][2], st2[si][tjc][3]);
        *reinterpret_cast<u32x2*>(sb + tl * 128 + ((si * 32 + g * 8) ^ vswz)) = w;
      }
    }
    asm volatile("s_waitcnt lgkmcnt(0)" ::: "memory");

    // PV: oa[tjc] += av[kc] x P^T fragment
    f32x4 oa0 = fz, oa1 = fz;
    {
      const f16x8 pa00 = *reinterpret_cast<const f16x8*>(
          sb + l15 * 128 + ((g * 16) ^ vswz));
      const f16x8 pa10 = *reinterpret_cast<const f16x8*>(
          sb + (16 + l15) * 128 + ((g * 16) ^ vswz));
      oa0 = mfma32(av0, pa00, oa0);
      oa1 = mfma32(av0, pa10, oa1);
      const f16x8 pa01 = *reinterpret_cast<const f16x8*>(
          sb + l15 * 128 + ((64 + g * 16) ^ vswz));
      const f16x8 pa11 = *reinterpret_cast<const f16x8*>(
          sb + (16 + l15) * 128 + ((64 + g * 16) ^ vswz));
      oa0 = mfma32(av1, pa01, oa0);
      oa1 = mfma32(av1, pa11, oa1);
    }

    // pack o: lane holds o[t][c = wv*16 + g*4 + r]
    if (tjp == 0) {
      opk[0][0] = pk2(oa0[0], oa0[1]); opk[0][1] = pk2(oa0[2], oa0[3]);
      opk[1][0] = pk2(oa1[0], oa1[1]); opk[1][1] = pk2(oa1[2], oa1[3]);
    } else {
      opk[2][0] = pk2(oa0[0], oa0[1]); opk[2][1] = pk2(oa0[2], oa0[3]);
      opk[3][0] = pk2(oa1[0], oa1[1]); opk[3][1] = pk2(oa1[2], oa1[3]);
    }
  }
  __syncthreads();   // all waves done reading x from xsm -> becomes o buffer

  // ---- write o (this head) to xsm: ch = wv*16 + g*4 + r ----
#pragma unroll
  for (int tj = 0; tj < 4; ++tj) {
    const int t = tj * 16 + l15;
    u32x2 w0; w0[0] = opk[tj][0]; w0[1] = opk[tj][1];
    *reinterpret_cast<u32x2*>(xsm + t * 256 + ((wv * 32 + g * 8) ^ ((t & 15) << 4))) = w0;
  }
  __syncthreads();

  // ---------------- 1x1x1 conv GEMM + store (16 couts per wave) ----------------
  f32x4 cacc[4] = {fz, fz, fz, fz};
  const int cout = wv * 16 + l15;
#pragma unroll
  for (int kk = 0; kk < 4; ++kk) {
    const f16x8 bfr = *reinterpret_cast<const f16x8*>(wc + cout * 128 + kk * 32 + g * 8);
#pragma unroll
    for (int ri = 0; ri < 4; ++ri) {
      const f16x8 a = *reinterpret_cast<const f16x8*>(
          xsm + (ri * 16 + l15) * 256 + ((kk * 64 + g * 16) ^ swzA));
      cacc[ri] = mfma32(a, bfr, cacc[ri]);
    }
  }
  // rows: t = ri*16 + g*4 + r -> i0 = ri (z), i1 = g (y), i2 = r (x)
  const int y = hh * 4 + g;
  if (y < 62) {
    const float bias = cb[cout];
#pragma unroll
    for (int ri = 0; ri < 4; ++ri) {
      const int z = dd * 4 + ri;
      float* dst = outg + (((size_t)(bb * 128 + cout) * 32 + (size_t)z) * 3844
                           + (size_t)(y * 62 + ww * 4));
      float2 lo; lo.x = cacc[ri][0] + bias; lo.y = cacc[ri][1] + bias;
      *reinterpret_cast<float2*>(dst) = lo;
      if (ww < 15) {
        float2 hi; hi.x = cacc[ri][2] + bias; hi.y = cacc[ri][3] + bias;
        *reinterpret_cast<float2*>(dst + 2) = hi;
      }
    }
  }
}

extern "C" void kernel_launch(void* const* d_in, const int* in_sizes, int n_in,
                              void* d_out, int out_size, void* d_ws, size_t ws_size,
                              hipStream_t stream) {
  const float* x  = (const float*)d_in[0];
  const float* qw = (const float*)d_in[1];
  const float* qb = (const float*)d_in[2];
  const float* cw = (const float*)d_in[3];
  const float* cb = (const float*)d_in[4];
  float* out = (float*)d_out;

  if (ws_size < (size_t)(384 * 128 + 128 * 128) * sizeof(_Float16)) return;
  _Float16* wq = (_Float16*)d_ws;
  _Float16* wc = wq + 384 * 128;

  cvt_weights<<<192, 256, 0, stream>>>(qw, cw, wq, wc);
  win_attn<<<4096, 512, 0, stream>>>(x, wq, qb, wc, cb, out);
}

// Round 17
// 174.754 us; speedup vs baseline: 2.2375x; 2.2375x over previous
//
#include <hip/hip_runtime.h>

typedef _Float16 f16x8 __attribute__((ext_vector_type(8)));
typedef _Float16 f16x4 __attribute__((ext_vector_type(4)));
typedef __fp16   fp16x2 __attribute__((ext_vector_type(2)));
typedef float    f32x4 __attribute__((ext_vector_type(4)));
typedef unsigned int u32x2 __attribute__((ext_vector_type(2)));

__device__ __forceinline__ f32x4 mfma32(f16x8 a, f16x8 b, f32x4 c) {
  return __builtin_amdgcn_mfma_f32_16x16x32_f16(a, b, c, 0, 0, 0);
}
__device__ __forceinline__ f32x4 mfma16(f16x4 a, f16x4 b, f32x4 c) {
#if __has_builtin(__builtin_amdgcn_mfma_f32_16x16x16f16)
  return __builtin_amdgcn_mfma_f32_16x16x16f16(a, b, c, 0, 0, 0);
#else
  f32x4 d;
  asm volatile("v_mfma_f32_16x16x16_f16 %0, %1, %2, %3"
               : "=v"(d) : "v"(a), "v"(b), "v"(c));
  return d;
#endif
}

__device__ __forceinline__ unsigned pk2(float a, float b) {
  union { fp16x2 h; unsigned u; } cv;
  cv.h = __builtin_amdgcn_cvt_pkrtz(a, b);
  return cv.u;
}

// hardware transpose read: per-lane vaddr (32-bit LDS byte offset) = base + 8*lane;
// delivers, for lane l, elems j=0..3 = lds_elem[(l&15) + 16*j + 64*(l>>4)] rel. to base
#define TR_READ(dst, addr, OFF) \
  asm volatile("ds_read_b64_tr_b16 %0, %1 offset:" OFF \
               : "=v"(dst) : "v"(addr) : "memory")

// ---- pre-convert weights to fp16 in workspace (L2-resident reuse) ----
__global__ void cvt_weights(const float* __restrict__ qw, const float* __restrict__ cw,
                            _Float16* __restrict__ wq, _Float16* __restrict__ wc) {
  const int i = blockIdx.x * 256 + threadIdx.x;
  if (i < 384 * 128) wq[i] = (_Float16)qw[i];
  if (i < 128 * 128) wc[i] = (_Float16)cw[i];
}

// TWO 4x4x4 windows per block (wid = 2wp, 2wp+1: same bb/dd/hh, adjacent ww ->
// contiguous 32-float strips, L2-friendly), software-pipelined: w1's global
// loads issue after attn(w0) and its LDS stage-write overlaps o(w0); conv(w0)
// and QKV(w1) share a phase (disjoint buffers). Grid 2048 (4 rounds/CU not 8).
// 512 threads = 8 waves; wave wv owns head h=wv. v in REGISTERS (R16-verified
// shfl redistribution) -> wsm 4KB/wave. Occupancy is hard-capped at 16
// waves/CU (R16: 24 waves needs <=85 regs -> massive spill); (512,4) = 128-reg
// budget, no spill (R12-proven).
// LDS (64KB, 2 blocks/CU):
//   xsm[2][16KB]: per-window x/o buffer [64 t][128 ch], byte = t*256 + (2ch ^ ((t&15)<<4))
//   wsm[wv] (4KB/wave): [0,2048) k as [si][16ch][16tok] (tr-read layout),
//                       [2048,4096) q same; P chunk [32t][64s] overlays [0,4096):
//                         byte = t_local*128 + (2s ^ ((l15&7)<<4))
__global__ void __launch_bounds__(512, 4)
win_attn(const float* __restrict__ xg, const _Float16* __restrict__ wq,
         const float* __restrict__ qbias, const _Float16* __restrict__ wc,
         const float* __restrict__ cb, float* __restrict__ outg)
{
  __shared__ char xsm[2][16384];
  __shared__ char wsm[8][4096];

  const int tid  = threadIdx.x;
  const int lane = tid & 63;
  const int wv   = tid >> 6;          // 0..7 = head
  const int l15  = lane & 15;
  const int g    = lane >> 4;

  // XCD-bijective swizzle over window PAIRS (2048 % 8 == 0)
  const int raw = blockIdx.x;
  const int wp  = ((raw & 7) << 8) | (raw >> 3);
  const int wid0 = wp * 2;
  const int ww0 = wid0 & 15, hh = (wid0 >> 4) & 15, dd = (wid0 >> 8) & 7, bb = wid0 >> 11;
  const int ww1 = ww0 + 1;            // ww0 even <= 14, no carry into hh

  unsigned long long pm0 = 0ull, pm1 = 0ull;   // pad flag per token
  if (hh == 15)  { pm0 |= 0xFF00FF00FF00FF00ull; pm1 |= 0xFF00FF00FF00FF00ull; }
  if (ww1 == 15)   pm1 |= 0xCCCCCCCCCCCCCCCCull;

  const f32x4 fz = {0.f, 0.f, 0.f, 0.f};
  const float LOG2E = 1.4426950408889634f;
  const int swzA = l15 << 4;
  const int vswz = (l15 & 7) << 4;              // P-chunk swizzle

  char* sb = wsm[wv];
  const unsigned sb32 = (unsigned)(unsigned long long)sb;   // LDS byte offset
  const unsigned trb  = sb32 + 8u * (unsigned)lane;

  // staging geometry (shared by both windows)
  const int m4 = lane & 3, q4 = lane >> 2;
  const int i0 = q4 >> 2, i1 = q4 & 3;
  const int z = dd * 4 + i0, y = hh * 4 + i1;
  const bool yv = (y < 62);

  // ---- issue global loads for window with col base wwl ----
  auto stage_loads = [&](int wwl, float (&va)[4][4]) {
    const bool full = (wwl < 15);
#pragma unroll
    for (int it = 0; it < 4; ++it) {
      const int c = wv * 16 + it * 4 + m4;
      const float* src = xg + (((size_t)(bb * 128 + c) * 32 + (size_t)z) * 3844
                               + (size_t)(y * 62 + wwl * 4));
      float a0 = 0.f, a1 = 0.f, a2 = 0.f, a3 = 0.f;
      if (yv) {
        const float2 lo = *reinterpret_cast<const float2*>(src);
        a0 = lo.x; a1 = lo.y;
        if (full) {
          const float2 hi = *reinterpret_cast<const float2*>(src + 2);
          a2 = hi.x; a3 = hi.y;
        }
      }
      va[it][0] = a0; va[it][1] = a1; va[it][2] = a2; va[it][3] = a3;
    }
  };
  // ---- 4x4 lane-quad transpose + packed b64 write into xb ----
  auto stage_write = [&](char* xb, float (&va)[4][4]) {
#pragma unroll
    for (int it = 0; it < 4; ++it) {
      float v0 = va[it][0], v1 = va[it][1], v2 = va[it][2], v3 = va[it][3];
      float t0 = __shfl_xor((m4 & 1) ? v0 : v1, 1);
      float t1 = __shfl_xor((m4 & 1) ? v2 : v3, 1);
      if (m4 & 1) { v0 = t0; v2 = t1; } else { v1 = t0; v3 = t1; }
      float t2 = __shfl_xor((m4 & 2) ? v0 : v2, 2);
      float t3 = __shfl_xor((m4 & 2) ? v1 : v3, 2);
      if (m4 & 2) { v0 = t2; v1 = t3; } else { v2 = t2; v3 = t3; }
      f16x4 pk; pk[0] = (_Float16)v0; pk[1] = (_Float16)v1;
                pk[2] = (_Float16)v2; pk[3] = (_Float16)v3;
      const int c0 = wv * 16 + it * 4;         // lane holds xs[t=lane][c0..c0+3]
      *reinterpret_cast<f16x4*>(xb + ((lane * 256 + 2 * c0) ^ ((lane & 15) << 4))) = pk;
    }
  };

  // ---- per-window: QKV GEMM -> attention; fills opk ----
  auto qkv_attn = [&](const char* xb, unsigned long long pm, unsigned (&opk)[4][2]) {
    f16x8 av0, av1;   // v fragments (registers; R16-verified mapping)
#pragma unroll
    for (int co = 0; co < 3; ++co) {
      f32x4 acc[4] = {fz, fz, fz, fz};
      const int col = co * 128 + wv * 16 + l15;
      __builtin_amdgcn_s_setprio(1);
#pragma unroll
      for (int kk = 0; kk < 4; ++kk) {
        const f16x8 bfr = *reinterpret_cast<const f16x8*>(wq + col * 128 + kk * 32 + g * 8);
#pragma unroll
        for (int ri = 0; ri < 4; ++ri) {
          const f16x8 a = *reinterpret_cast<const f16x8*>(
              xb + (ri * 16 + l15) * 256 + ((kk * 64 + g * 16) ^ swzA));
          acc[ri] = mfma32(a, bfr, acc[ri]);
        }
      }
      __builtin_amdgcn_s_setprio(0);
      const float bias = qbias[col];

      if (co == 2) {
        unsigned vp[4][2];
#pragma unroll
        for (int ri = 0; ri < 4; ++ri) {
          vp[ri][0] = pk2(acc[ri][0] + bias, acc[ri][1] + bias);
          vp[ri][1] = pk2(acc[ri][2] + bias, acc[ri][3] + bias);
        }
        const int srcA = l15 + 32 * (g & 1);
        const bool hi = (g >= 2);
        {
          const unsigned a0 = __shfl(vp[0][0], srcA);
          const unsigned a1 = __shfl(vp[0][1], srcA);
          const unsigned a2 = __shfl(vp[0][0], srcA + 16);
          const unsigned a3 = __shfl(vp[0][1], srcA + 16);
          const unsigned b0 = __shfl(vp[1][0], srcA);
          const unsigned b1 = __shfl(vp[1][1], srcA);
          const unsigned b2 = __shfl(vp[1][0], srcA + 16);
          const unsigned b3 = __shfl(vp[1][1], srcA + 16);
          union { unsigned w[4]; f16x8 v; } u;
          u.w[0] = hi ? b0 : a0; u.w[1] = hi ? b1 : a1;
          u.w[2] = hi ? b2 : a2; u.w[3] = hi ? b3 : a3;
          av0 = u.v;
        }
        {
          const unsigned a0 = __shfl(vp[2][0], srcA);
          const unsigned a1 = __shfl(vp[2][1], srcA);
          const unsigned a2 = __shfl(vp[2][0], srcA + 16);
          const unsigned a3 = __shfl(vp[2][1], srcA + 16);
          const unsigned b0 = __shfl(vp[3][0], srcA);
          const unsigned b1 = __shfl(vp[3][1], srcA);
          const unsigned b2 = __shfl(vp[3][0], srcA + 16);
          const unsigned b3 = __shfl(vp[3][1], srcA + 16);
          union { unsigned w[4]; f16x8 v; } u;
          u.w[0] = hi ? b0 : a0; u.w[1] = hi ? b1 : a1;
          u.w[2] = hi ? b2 : a2; u.w[3] = hi ? b3 : a3;
          av1 = u.v;
        }
      } else {
        const int base = (co == 0) ? 2048 : 0;
        const float sc = (co == 0) ? 0.25f : 1.0f;   // fold softmax scale into q
#pragma unroll
        for (int ri = 0; ri < 4; ++ri) {
          const int off = ri * 512 + l15 * 32 + g * 8;  // bytes
          u32x2 w;
          w[0] = pk2((acc[ri][0] + bias) * sc, (acc[ri][1] + bias) * sc);
          w[1] = pk2((acc[ri][2] + bias) * sc, (acc[ri][3] + bias) * sc);
          *reinterpret_cast<u32x2*>(sb + base + off) = w;
        }
      }
    }
    asm volatile("s_waitcnt lgkmcnt(0)" ::: "memory");

    f16x4 ka[4], qa[4];
    TR_READ(ka[0], trb, "0");
    TR_READ(ka[1], trb, "512");
    TR_READ(ka[2], trb, "1024");
    TR_READ(ka[3], trb, "1536");
    TR_READ(qa[0], trb, "2048");
    TR_READ(qa[1], trb, "2560");
    TR_READ(qa[2], trb, "3072");
    TR_READ(qa[3], trb, "3584");
    asm volatile("s_waitcnt lgkmcnt(0)" ::: "memory");
    __builtin_amdgcn_sched_barrier(0);           // rule #18: fence tr_read -> mfma

#pragma unroll
    for (int tjp = 0; tjp < 2; ++tjp) {
      const int tj0 = 2 * tjp, tj1 = 2 * tjp + 1;
      f32x4 st2[4][2];
#pragma unroll
      for (int si = 0; si < 4; ++si) {
        st2[si][0] = mfma16(ka[si], qa[tj0], fz);
        st2[si][1] = mfma16(ka[si], qa[tj1], fz);
      }

      if (pm) {
#pragma unroll
        for (int tjc = 0; tjc < 2; ++tjc) {
          const int t = (2 * tjp + tjc) * 16 + l15;
          const unsigned ft = (unsigned)(pm >> t) & 1u;
#pragma unroll
          for (int si = 0; si < 4; ++si)
#pragma unroll
            for (int r = 0; r < 4; ++r) {
              const int s = si * 16 + g * 4 + r;
              const unsigned fs = (unsigned)(pm >> s) & 1u;
              if (fs != ft) st2[si][tjc][r] -= 1000.f;
            }
        }
      }

#pragma unroll
      for (int tjc = 0; tjc < 2; ++tjc) {
        float mx = st2[0][tjc][0];
#pragma unroll
        for (int si = 0; si < 4; ++si)
#pragma unroll
          for (int r = 0; r < 4; ++r) mx = fmaxf(mx, st2[si][tjc][r]);
        mx = fmaxf(mx, __shfl_xor(mx, 16));
        mx = fmaxf(mx, __shfl_xor(mx, 32));
        float sum = 0.f;
#pragma unroll
        for (int si = 0; si < 4; ++si)
#pragma unroll
          for (int r = 0; r < 4; ++r) {
            const float e = __builtin_amdgcn_exp2f((st2[si][tjc][r] - mx) * LOG2E);
            st2[si][tjc][r] = e; sum += e;
          }
        sum += __shfl_xor(sum, 16);
        sum += __shfl_xor(sum, 32);
        const float inv = __builtin_amdgcn_rcpf(sum);
#pragma unroll
        for (int si = 0; si < 4; ++si)
#pragma unroll
          for (int r = 0; r < 4; ++r) st2[si][tjc][r] *= inv;
      }

      // write P chunk [32 t_local][64 s]: byte = t_local*128 + (2s ^ vswz)
#pragma unroll
      for (int tjc = 0; tjc < 2; ++tjc) {
        const int tl = tjc * 16 + l15;
#pragma unroll
        for (int si = 0; si < 4; ++si) {
          u32x2 w;
          w[0] = pk2(st2[si][tjc][0], st2[si][tjc][1]);
          w[1] = pk2(st2[si][tjc][2], st2[si][tjc][3]);
          *reinterpret_cast<u32x2*>(sb + tl * 128 + ((si * 32 + g * 8) ^ vswz)) = w;
        }
      }
      asm volatile("s_waitcnt lgkmcnt(0)" ::: "memory");

      f32x4 oa0 = fz, oa1 = fz;
      {
        const f16x8 pa00 = *reinterpret_cast<const f16x8*>(
            sb + l15 * 128 + ((g * 16) ^ vswz));
        const f16x8 pa10 = *reinterpret_cast<const f16x8*>(
            sb + (16 + l15) * 128 + ((g * 16) ^ vswz));
        __builtin_amdgcn_s_setprio(1);
        oa0 = mfma32(av0, pa00, oa0);
        oa1 = mfma32(av0, pa10, oa1);
        const f16x8 pa01 = *reinterpret_cast<const f16x8*>(
            sb + l15 * 128 + ((64 + g * 16) ^ vswz));
        const f16x8 pa11 = *reinterpret_cast<const f16x8*>(
            sb + (16 + l15) * 128 + ((64 + g * 16) ^ vswz));
        oa0 = mfma32(av1, pa01, oa0);
        oa1 = mfma32(av1, pa11, oa1);
        __builtin_amdgcn_s_setprio(0);
      }

      if (tjp == 0) {
        opk[0][0] = pk2(oa0[0], oa0[1]); opk[0][1] = pk2(oa0[2], oa0[3]);
        opk[1][0] = pk2(oa1[0], oa1[1]); opk[1][1] = pk2(oa1[2], oa1[3]);
      } else {
        opk[2][0] = pk2(oa0[0], oa0[1]); opk[2][1] = pk2(oa0[2], oa0[3]);
        opk[3][0] = pk2(oa1[0], oa1[1]); opk[3][1] = pk2(oa1[2], oa1[3]);
      }
      __builtin_amdgcn_sched_barrier(0);        // keep tj-pairs apart (st2 peak)
    }
  };

  auto write_o = [&](char* xb, unsigned (&opk)[4][2]) {
#pragma unroll
    for (int tj = 0; tj < 4; ++tj) {
      const int t = tj * 16 + l15;
      u32x2 w0; w0[0] = opk[tj][0]; w0[1] = opk[tj][1];
      *reinterpret_cast<u32x2*>(xb + t * 256 + ((wv * 32 + g * 8) ^ ((t & 15) << 4))) = w0;
    }
  };

  auto conv_store = [&](const char* xb, int wwl) {
    f32x4 cacc[4] = {fz, fz, fz, fz};
    const int cout = wv * 16 + l15;
    __builtin_amdgcn_s_setprio(1);
#pragma unroll
    for (int kk = 0; kk < 4; ++kk) {
      const f16x8 bfr = *reinterpret_cast<const f16x8*>(wc + cout * 128 + kk * 32 + g * 8);
#pragma unroll
      for (int ri = 0; ri < 4; ++ri) {
        const f16x8 a = *reinterpret_cast<const f16x8*>(
            xb + (ri * 16 + l15) * 256 + ((kk * 64 + g * 16) ^ swzA));
        cacc[ri] = mfma32(a, bfr, cacc[ri]);
      }
    }
    __builtin_amdgcn_s_setprio(0);
    // rows: t = ri*16 + g*4 + r -> i0 = ri (z), i1 = g (y), i2 = r (x)
    const int yy = hh * 4 + g;
    if (yy < 62) {
      const float bias = cb[cout];
#pragma unroll
      for (int ri = 0; ri < 4; ++ri) {
        const int zz = dd * 4 + ri;
        float* dst = outg + (((size_t)(bb * 128 + cout) * 32 + (size_t)zz) * 3844
                             + (size_t)(yy * 62 + wwl * 4));
        float2 lo; lo.x = cacc[ri][0] + bias; lo.y = cacc[ri][1] + bias;
        *reinterpret_cast<float2*>(dst) = lo;
        if (wwl < 15) {
          float2 hi; hi.x = cacc[ri][2] + bias; hi.y = cacc[ri][3] + bias;
          *reinterpret_cast<float2*>(dst + 2) = hi;
        }
      }
    }
  };

  // ================= pipelined 2-window schedule =================
  float va[4][4];
  stage_loads(ww0, va);
  stage_write(xsm[0], va);
  __syncthreads();                       // buf0.x ready

  unsigned opk[4][2];
  qkv_attn(xsm[0], pm0, opk);            // window 0 compute
  stage_loads(ww1, va);                  // issue w1 loads (hide under barrier+o)
  __syncthreads();                       // all waves done reading buf0.x
  write_o(xsm[0], opk);
  stage_write(xsm[1], va);               // w1 stage overlaps o(w0)
  __syncthreads();                       // buf0.o + buf1.x ready

  conv_store(xsm[0], ww0);               // conv(w0) ...
  qkv_attn(xsm[1], pm1, opk);            // ... interleaves with QKV(w1)
  __syncthreads();                       // all waves done reading buf1.x
  write_o(xsm[1], opk);
  __syncthreads();                       // buf1.o ready
  conv_store(xsm[1], ww1);
}

extern "C" void kernel_launch(void* const* d_in, const int* in_sizes, int n_in,
                              void* d_out, int out_size, void* d_ws, size_t ws_size,
                              hipStream_t stream) {
  const float* x  = (const float*)d_in[0];
  const float* qw = (const float*)d_in[1];
  const float* qb = (const float*)d_in[2];
  const float* cw = (const float*)d_in[3];
  const float* cb = (const float*)d_in[4];
  float* out = (float*)d_out;

  if (ws_size < (size_t)(384 * 128 + 128 * 128) * sizeof(_Float16)) return;
  _Float16* wq = (_Float16*)d_ws;
  _Float16* wc = wq + 384 * 128;

  cvt_weights<<<192, 256, 0, stream>>>(qw, cw, wq, wc);
  win_attn<<<2048, 512, 0, stream>>>(x, wq, qb, wc, cb, out);
}

// Round 18
// 172.671 us; speedup vs baseline: 2.2645x; 1.0121x over previous
//
#include <hip/hip_runtime.h>

typedef _Float16 f16x8 __attribute__((ext_vector_type(8)));
typedef _Float16 f16x4 __attribute__((ext_vector_type(4)));
typedef __fp16   fp16x2 __attribute__((ext_vector_type(2)));
typedef float    f32x4 __attribute__((ext_vector_type(4)));
typedef unsigned int u32x2 __attribute__((ext_vector_type(2)));

__device__ __forceinline__ f32x4 mfma32(f16x8 a, f16x8 b, f32x4 c) {
  return __builtin_amdgcn_mfma_f32_16x16x32_f16(a, b, c, 0, 0, 0);
}
__device__ __forceinline__ f32x4 mfma16(f16x4 a, f16x4 b, f32x4 c) {
#if __has_builtin(__builtin_amdgcn_mfma_f32_16x16x16f16)
  return __builtin_amdgcn_mfma_f32_16x16x16f16(a, b, c, 0, 0, 0);
#else
  f32x4 d;
  asm volatile("v_mfma_f32_16x16x16_f16 %0, %1, %2, %3"
               : "=v"(d) : "v"(a), "v"(b), "v"(c));
  return d;
#endif
}

__device__ __forceinline__ unsigned pk2(float a, float b) {
  union { fp16x2 h; unsigned u; } cv;
  cv.h = __builtin_amdgcn_cvt_pkrtz(a, b);
  return cv.u;
}

// hardware transpose read: per-lane vaddr (32-bit LDS byte offset) = base + 8*lane;
// delivers, for lane l, elems j=0..3 = lds_elem[(l&15) + 16*j + 64*(l>>4)] rel. to base
#define TR_READ(dst, addr, OFF) \
  asm volatile("ds_read_b64_tr_b16 %0, %1 offset:" OFF \
               : "=v"(dst) : "v"(addr) : "memory")

// ---- pre-convert weights to fp16 in workspace (L2-resident reuse) ----
__global__ void cvt_weights(const float* __restrict__ qw, const float* __restrict__ cw,
                            _Float16* __restrict__ wq, _Float16* __restrict__ wc) {
  const int i = blockIdx.x * 256 + threadIdx.x;
  if (i < 384 * 128) wq[i] = (_Float16)qw[i];
  if (i < 128 * 128) wc[i] = (_Float16)cw[i];
}

// TWO windows per block, software-pipelined (grid 2048). R17 lesson: the
// pipeline concept is sound but va[4][4] held across w0's WHOLE compute
// spilled ~12 dw/thread. R18 scopes va's lifetime to [after w0 tr-reads ->
// stage_write after w0's o], i.e. only across the attn chunks — exactly the
// HBM latency window to hide. v back in LDS (R12 layout) to drop the vp/av
// shuffle pressure. LDS 80KB = 2 blocks/CU (hard cap anyway per R16).
// LDS (80KB, 2 blocks/CU):
//   xsm[2][16KB]: per-window x/o buffer [64 t][128 ch], byte = t*256 + (2ch ^ ((t&15)<<4))
//   wsm[wv] (6KB/wave): [0,2048) k as [si][16ch][16tok] (tr-read layout),
//                       [2048,4096) q same; P chunk [32t][64s] overlays [0,4096):
//                         byte = t_local*128 + (2s ^ ((l15&7)<<4))
//                       [4096,6144) v as [c][s]: byte = c*128 + (2s ^ ((c&7)<<4))
__global__ void __launch_bounds__(512, 4)
win_attn(const float* __restrict__ xg, const _Float16* __restrict__ wq,
         const float* __restrict__ qbias, const _Float16* __restrict__ wc,
         const float* __restrict__ cb, float* __restrict__ outg)
{
  __shared__ char xsm[2][16384];
  __shared__ char wsm[8][6144];

  const int tid  = threadIdx.x;
  const int lane = tid & 63;
  const int wv   = tid >> 6;          // 0..7 = head
  const int l15  = lane & 15;
  const int g    = lane >> 4;

  // XCD-bijective swizzle over window PAIRS (2048 % 8 == 0)
  const int raw = blockIdx.x;
  const int wp  = ((raw & 7) << 8) | (raw >> 3);
  const int wid0 = wp * 2;
  const int ww0 = wid0 & 15, hh = (wid0 >> 4) & 15, dd = (wid0 >> 8) & 7, bb = wid0 >> 11;
  const int ww1 = ww0 + 1;            // ww0 even <= 14, no carry into hh

  unsigned long long pm0 = 0ull, pm1 = 0ull;   // pad flag per token
  if (hh == 15)  { pm0 |= 0xFF00FF00FF00FF00ull; pm1 |= 0xFF00FF00FF00FF00ull; }
  if (ww1 == 15)   pm1 |= 0xCCCCCCCCCCCCCCCCull;

  const f32x4 fz = {0.f, 0.f, 0.f, 0.f};
  const float LOG2E = 1.4426950408889634f;
  const int swzA = l15 << 4;
  const int vswz = (l15 & 7) << 4;              // v / P-chunk swizzle

  char* sb = wsm[wv];
  const unsigned sb32 = (unsigned)(unsigned long long)sb;   // LDS byte offset
  const unsigned trb  = sb32 + 8u * (unsigned)lane;

  // staging geometry (shared by both windows)
  const int m4 = lane & 3, q4 = lane >> 2;
  const int i0 = q4 >> 2, i1 = q4 & 3;
  const int z = dd * 4 + i0, y = hh * 4 + i1;
  const bool yv = (y < 62);

  auto stage_loads = [&](int wwl, float (&va)[4][4]) {
    const bool full = (wwl < 15);
#pragma unroll
    for (int it = 0; it < 4; ++it) {
      const int c = wv * 16 + it * 4 + m4;
      const float* src = xg + (((size_t)(bb * 128 + c) * 32 + (size_t)z) * 3844
                               + (size_t)(y * 62 + wwl * 4));
      float a0 = 0.f, a1 = 0.f, a2 = 0.f, a3 = 0.f;
      if (yv) {
        const float2 lo = *reinterpret_cast<const float2*>(src);
        a0 = lo.x; a1 = lo.y;
        if (full) {
          const float2 hi = *reinterpret_cast<const float2*>(src + 2);
          a2 = hi.x; a3 = hi.y;
        }
      }
      va[it][0] = a0; va[it][1] = a1; va[it][2] = a2; va[it][3] = a3;
    }
  };
  auto stage_write = [&](char* xb, float (&va)[4][4]) {
#pragma unroll
    for (int it = 0; it < 4; ++it) {
      float v0 = va[it][0], v1 = va[it][1], v2 = va[it][2], v3 = va[it][3];
      float t0 = __shfl_xor((m4 & 1) ? v0 : v1, 1);
      float t1 = __shfl_xor((m4 & 1) ? v2 : v3, 1);
      if (m4 & 1) { v0 = t0; v2 = t1; } else { v1 = t0; v3 = t1; }
      float t2 = __shfl_xor((m4 & 2) ? v0 : v2, 2);
      float t3 = __shfl_xor((m4 & 2) ? v1 : v3, 2);
      if (m4 & 2) { v0 = t2; v1 = t3; } else { v2 = t2; v3 = t3; }
      f16x4 pk; pk[0] = (_Float16)v0; pk[1] = (_Float16)v1;
                pk[2] = (_Float16)v2; pk[3] = (_Float16)v3;
      const int c0 = wv * 16 + it * 4;         // lane holds xs[t=lane][c0..c0+3]
      *reinterpret_cast<f16x4*>(xb + ((lane * 256 + 2 * c0) ^ ((lane & 15) << 4))) = pk;
    }
  };

  // ---- QKV GEMM (q,k -> tr layout; v -> [c][s] LDS) + tr/av fragment loads ----
  auto qkv_part1 = [&](const char* xb, f16x4 (&ka)[4], f16x4 (&qa)[4],
                       f16x8& av0, f16x8& av1) {
#pragma unroll
    for (int co = 0; co < 3; ++co) {
      f32x4 acc[4] = {fz, fz, fz, fz};
      const int col = co * 128 + wv * 16 + l15;
      __builtin_amdgcn_s_setprio(1);
#pragma unroll
      for (int kk = 0; kk < 4; ++kk) {
        const f16x8 bfr = *reinterpret_cast<const f16x8*>(wq + col * 128 + kk * 32 + g * 8);
#pragma unroll
        for (int ri = 0; ri < 4; ++ri) {
          const f16x8 a = *reinterpret_cast<const f16x8*>(
              xb + (ri * 16 + l15) * 256 + ((kk * 64 + g * 16) ^ swzA));
          acc[ri] = mfma32(a, bfr, acc[ri]);
        }
      }
      __builtin_amdgcn_s_setprio(0);
      const float bias = qbias[col];

      if (co == 2) {
        // v -> [c][s]: lane holds v[t = ri*16+g*4+r][c = l15]
#pragma unroll
        for (int ri = 0; ri < 4; ++ri) {
          const int s0 = ri * 16 + g * 4;
          *reinterpret_cast<unsigned*>(sb + 4096 + l15 * 128 + ((2 * s0) ^ vswz))
              = pk2(acc[ri][0] + bias, acc[ri][1] + bias);
          *reinterpret_cast<unsigned*>(sb + 4096 + l15 * 128 + ((2 * (s0 + 2)) ^ vswz))
              = pk2(acc[ri][2] + bias, acc[ri][3] + bias);
        }
      } else {
        const int base = (co == 0) ? 2048 : 0;
        const float sc = (co == 0) ? 0.25f : 1.0f;   // fold softmax scale into q
#pragma unroll
        for (int ri = 0; ri < 4; ++ri) {
          const int off = ri * 512 + l15 * 32 + g * 8;  // bytes
          u32x2 w;
          w[0] = pk2((acc[ri][0] + bias) * sc, (acc[ri][1] + bias) * sc);
          w[1] = pk2((acc[ri][2] + bias) * sc, (acc[ri][3] + bias) * sc);
          *reinterpret_cast<u32x2*>(sb + base + off) = w;
        }
      }
    }
    asm volatile("s_waitcnt lgkmcnt(0)" ::: "memory");

    TR_READ(ka[0], trb, "0");
    TR_READ(ka[1], trb, "512");
    TR_READ(ka[2], trb, "1024");
    TR_READ(ka[3], trb, "1536");
    TR_READ(qa[0], trb, "2048");
    TR_READ(qa[1], trb, "2560");
    TR_READ(qa[2], trb, "3072");
    TR_READ(qa[3], trb, "3584");
    av0 = *reinterpret_cast<const f16x8*>(sb + 4096 + l15 * 128 + ((g * 16) ^ vswz));
    av1 = *reinterpret_cast<const f16x8*>(sb + 4096 + l15 * 128 + ((64 + g * 16) ^ vswz));
    asm volatile("s_waitcnt lgkmcnt(0)" ::: "memory");
    __builtin_amdgcn_sched_barrier(0);           // rule #18: fence tr_read -> mfma
  };

  // ---- two tj-pair chunks: S^T -> softmax -> P chunk -> PV; fills opk ----
  auto attn_chunks = [&](unsigned long long pm, f16x4 (&ka)[4], f16x4 (&qa)[4],
                         f16x8 av0, f16x8 av1, unsigned (&opk)[4][2]) {
#pragma unroll
    for (int tjp = 0; tjp < 2; ++tjp) {
      const int tj0 = 2 * tjp, tj1 = 2 * tjp + 1;
      f32x4 st2[4][2];
#pragma unroll
      for (int si = 0; si < 4; ++si) {
        st2[si][0] = mfma16(ka[si], qa[tj0], fz);
        st2[si][1] = mfma16(ka[si], qa[tj1], fz);
      }

      if (pm) {
#pragma unroll
        for (int tjc = 0; tjc < 2; ++tjc) {
          const int t = (2 * tjp + tjc) * 16 + l15;
          const unsigned ft = (unsigned)(pm >> t) & 1u;
#pragma unroll
          for (int si = 0; si < 4; ++si)
#pragma unroll
            for (int r = 0; r < 4; ++r) {
              const int s = si * 16 + g * 4 + r;
              const unsigned fs = (unsigned)(pm >> s) & 1u;
              if (fs != ft) st2[si][tjc][r] -= 1000.f;
            }
        }
      }

#pragma unroll
      for (int tjc = 0; tjc < 2; ++tjc) {
        float mx = st2[0][tjc][0];
#pragma unroll
        for (int si = 0; si < 4; ++si)
#pragma unroll
          for (int r = 0; r < 4; ++r) mx = fmaxf(mx, st2[si][tjc][r]);
        mx = fmaxf(mx, __shfl_xor(mx, 16));
        mx = fmaxf(mx, __shfl_xor(mx, 32));
        float sum = 0.f;
#pragma unroll
        for (int si = 0; si < 4; ++si)
#pragma unroll
          for (int r = 0; r < 4; ++r) {
            const float e = __builtin_amdgcn_exp2f((st2[si][tjc][r] - mx) * LOG2E);
            st2[si][tjc][r] = e; sum += e;
          }
        sum += __shfl_xor(sum, 16);
        sum += __shfl_xor(sum, 32);
        const float inv = __builtin_amdgcn_rcpf(sum);
#pragma unroll
        for (int si = 0; si < 4; ++si)
#pragma unroll
          for (int r = 0; r < 4; ++r) st2[si][tjc][r] *= inv;
      }

      // write P chunk [32 t_local][64 s]: byte = t_local*128 + (2s ^ vswz)
#pragma unroll
      for (int tjc = 0; tjc < 2; ++tjc) {
        const int tl = tjc * 16 + l15;
#pragma unroll
        for (int si = 0; si < 4; ++si) {
          u32x2 w;
          w[0] = pk2(st2[si][tjc][0], st2[si][tjc][1]);
          w[1] = pk2(st2[si][tjc][2], st2[si][tjc][3]);
          *reinterpret_cast<u32x2*>(sb + tl * 128 + ((si * 32 + g * 8) ^ vswz)) = w;
        }
      }
      asm volatile("s_waitcnt lgkmcnt(0)" ::: "memory");

      f32x4 oa0 = fz, oa1 = fz;
      {
        const f16x8 pa00 = *reinterpret_cast<const f16x8*>(
            sb + l15 * 128 + ((g * 16) ^ vswz));
        const f16x8 pa10 = *reinterpret_cast<const f16x8*>(
            sb + (16 + l15) * 128 + ((g * 16) ^ vswz));
        __builtin_amdgcn_s_setprio(1);
        oa0 = mfma32(av0, pa00, oa0);
        oa1 = mfma32(av0, pa10, oa1);
        const f16x8 pa01 = *reinterpret_cast<const f16x8*>(
            sb + l15 * 128 + ((64 + g * 16) ^ vswz));
        const f16x8 pa11 = *reinterpret_cast<const f16x8*>(
            sb + (16 + l15) * 128 + ((64 + g * 16) ^ vswz));
        oa0 = mfma32(av1, pa01, oa0);
        oa1 = mfma32(av1, pa11, oa1);
        __builtin_amdgcn_s_setprio(0);
      }

      if (tjp == 0) {
        opk[0][0] = pk2(oa0[0], oa0[1]); opk[0][1] = pk2(oa0[2], oa0[3]);
        opk[1][0] = pk2(oa1[0], oa1[1]); opk[1][1] = pk2(oa1[2], oa1[3]);
      } else {
        opk[2][0] = pk2(oa0[0], oa0[1]); opk[2][1] = pk2(oa0[2], oa0[3]);
        opk[3][0] = pk2(oa1[0], oa1[1]); opk[3][1] = pk2(oa1[2], oa1[3]);
      }
      __builtin_amdgcn_sched_barrier(0);        // keep tj-pairs apart (st2 peak)
    }
  };

  auto write_o = [&](char* xb, unsigned (&opk)[4][2]) {
#pragma unroll
    for (int tj = 0; tj < 4; ++tj) {
      const int t = tj * 16 + l15;
      u32x2 w0; w0[0] = opk[tj][0]; w0[1] = opk[tj][1];
      *reinterpret_cast<u32x2*>(xb + t * 256 + ((wv * 32 + g * 8) ^ ((t & 15) << 4))) = w0;
    }
  };

  auto conv_store = [&](const char* xb, int wwl) {
    f32x4 cacc[4] = {fz, fz, fz, fz};
    const int cout = wv * 16 + l15;
    __builtin_amdgcn_s_setprio(1);
#pragma unroll
    for (int kk = 0; kk < 4; ++kk) {
      const f16x8 bfr = *reinterpret_cast<const f16x8*>(wc + cout * 128 + kk * 32 + g * 8);
#pragma unroll
      for (int ri = 0; ri < 4; ++ri) {
        const f16x8 a = *reinterpret_cast<const f16x8*>(
            xb + (ri * 16 + l15) * 256 + ((kk * 64 + g * 16) ^ swzA));
        cacc[ri] = mfma32(a, bfr, cacc[ri]);
      }
    }
    __builtin_amdgcn_s_setprio(0);
    const int yy = hh * 4 + g;
    if (yy < 62) {
      const float bias = cb[cout];
#pragma unroll
      for (int ri = 0; ri < 4; ++ri) {
        const int zz = dd * 4 + ri;
        float* dst = outg + (((size_t)(bb * 128 + cout) * 32 + (size_t)zz) * 3844
                             + (size_t)(yy * 62 + wwl * 4));
        float2 lo; lo.x = cacc[ri][0] + bias; lo.y = cacc[ri][1] + bias;
        *reinterpret_cast<float2*>(dst) = lo;
        if (wwl < 15) {
          float2 hi; hi.x = cacc[ri][2] + bias; hi.y = cacc[ri][3] + bias;
          *reinterpret_cast<float2*>(dst + 2) = hi;
        }
      }
    }
  };

  // ================= pipelined 2-window schedule =================
  f16x4 ka[4], qa[4];
  f16x8 av0, av1;
  float va[4][4];
  unsigned opk[4][2];

  stage_loads(ww0, va);
  stage_write(xsm[0], va);
  __syncthreads();                       // buf0.x ready

  qkv_part1(xsm[0], ka, qa, av0, av1);   // w0 QKV + fragments
  stage_loads(ww1, va);                  // issue w1 loads NOW — hidden under chunks
  attn_chunks(pm0, ka, qa, av0, av1, opk);
  __syncthreads();                       // all waves done reading buf0.x
  write_o(xsm[0], opk);
  stage_write(xsm[1], va);               // consumes va (vmcnt waited here)
  __syncthreads();                       // buf0.o + buf1.x ready

  conv_store(xsm[0], ww0);               // conv(w0) interleaves with ...
  qkv_part1(xsm[1], ka, qa, av0, av1);   // ... QKV(w1) across waves
  attn_chunks(pm1, ka, qa, av0, av1, opk);
  __syncthreads();                       // all waves done reading buf1.x
  write_o(xsm[1], opk);
  __syncthreads();                       // buf1.o ready
  conv_store(xsm[1], ww1);
}

extern "C" void kernel_launch(void* const* d_in, const int* in_sizes, int n_in,
                              void* d_out, int out_size, void* d_ws, size_t ws_size,
                              hipStream_t stream) {
  const float* x  = (const float*)d_in[0];
  const float* qw = (const float*)d_in[1];
  const float* qb = (const float*)d_in[2];
  const float* cw = (const float*)d_in[3];
  const float* cb = (const float*)d_in[4];
  float* out = (float*)d_out;

  if (ws_size < (size_t)(384 * 128 + 128 * 128) * sizeof(_Float16)) return;
  _Float16* wq = (_Float16*)d_ws;
  _Float16* wc = wq + 384 * 128;

  cvt_weights<<<192, 256, 0, stream>>>(qw, cw, wq, wc);
  win_attn<<<2048, 512, 0, stream>>>(x, wq, qb, wc, cb, out);
}